// Round 2
// baseline (823.742 us; speedup 1.0000x reference)
//
#include <hip/hip_runtime.h>
#include <hip/hip_bf16.h>
#include <stdint.h>

typedef float f32x4 __attribute__((ext_vector_type(4)));
typedef float fvec4 __attribute__((ext_vector_type(4)));
typedef short bf16x8 __attribute__((ext_vector_type(8)));

#define HALF_K 24576
#define NUMELK 49152
#define BATCH  8192
#define BM 128
#define BK 64

__device__ __forceinline__ short f2bf(float f) {
  __hip_bfloat16 h = __float2bfloat16(f);
  return __builtin_bit_cast(short, h);
}

// ---------------- prep: Bws[256][49152] bf16 ----------------
// n<128 : Bws[n][k] = w_aff_W[n][k]           (combined-K order == w_feat order)
// n>=128: Bws[n][k] = b_aff_W[n-128][k<24576 ? k+24576 : k-24576]  (halves swapped)
__global__ __launch_bounds__(256)
void nnue_prep(const float* __restrict__ wW, const float* __restrict__ bW,
               short* __restrict__ Bws) {
  int k = (blockIdx.x * 256 + threadIdx.x) * 4;   // grid.x = 12288/256 = 48
  int n = blockIdx.y;                              // 0..255
  const float* src;
  if (n < 128) {
    src = wW + (size_t)n * NUMELK + k;
  } else {
    int kk = (k < HALF_K) ? (k + HALF_K) : (k - HALF_K);
    src = bW + (size_t)(n - 128) * NUMELK + kk;
  }
  fvec4 v = *(const fvec4*)src;
  unsigned a0 = (unsigned)(unsigned short)f2bf(v[0]) | ((unsigned)(unsigned short)f2bf(v[1]) << 16);
  unsigned a1 = (unsigned)(unsigned short)f2bf(v[2]) | ((unsigned)(unsigned short)f2bf(v[3]) << 16);
  uint2 o; o.x = a0; o.y = a1;
  *(uint2*)(Bws + (size_t)n * NUMELK + k) = o;
}

// ---------------- main GEMM: [8192 x 49152] x [49152 x 256] ----------------
// grid = (64, S). block (mt, ks) computes rows mt*128..+127 over K-chunk ks,
// writes exclusive fp32 partial[ks][m][n] (no atomics, deterministic).
// T14 structure: A is register-prefetched one iteration ahead; loads issued
// right after barrier-2, consumed (cvt) just before the next barrier-1, with
// the whole compute phase in between and no intervening barrier.
__global__ __launch_bounds__(512, 4)
void nnue_gemm(const float* __restrict__ white, const float* __restrict__ black,
               const short* __restrict__ Bws, float* __restrict__ partial,
               int kchunk) {
  __shared__ short Alds[BM * BK];   // [row][k], 16B chunks XOR-swizzled by (row&7)
  __shared__ short Blds[256 * BK];  // [col][k], 16B chunks XOR-swizzled by (col&7)

  const int t    = threadIdx.x;
  const int lane = t & 63;
  const int wid  = t >> 6;
  const int m0   = blockIdx.x * BM;
  const int ks   = blockIdx.y;
  const int k0   = ks * kchunk;

  f32x4 acc[4][4];
  const f32x4 zero = {0.f, 0.f, 0.f, 0.f};
#pragma unroll
  for (int i = 0; i < 4; ++i)
#pragma unroll
    for (int j = 0; j < 4; ++j) acc[i][j] = zero;

  const int arow = t >> 2;   // 0..127
  const int aq   = t & 3;    // 16 floats each
  const int wm = wid >> 2, wn = wid & 3;
  const int l15 = lane & 15, l4 = lane >> 4;

  const size_t arow_off = (size_t)(m0 + arow) * HALF_K + aq * 16;
  const int niter = kchunk / BK;

  // ---- prefetch A for kt=0
  fvec4 va0, va1, va2, va3;
  {
    const int kg = k0;
    const float* A; int ka;
    if (kg < HALF_K) { A = white; ka = kg; } else { A = black; ka = kg - HALF_K; }
    const float* asrc = A + arow_off + ka;
    va0 = ((const fvec4*)asrc)[0];
    va1 = ((const fvec4*)asrc)[1];
    va2 = ((const fvec4*)asrc)[2];
    va3 = ((const fvec4*)asrc)[3];
  }

  for (int kt = 0; kt < niter; ++kt) {
    const int kg = k0 + kt * BK;

    // ---- B just-in-time (L2/L3-resident): latency hides under barrier-1 skew
    uint4 bv[4];
    const short* bsrc = Bws + kg;
#pragma unroll
    for (int j = 0; j < 4; ++j) {
      int cid = t + j * 512;
      int col = cid >> 3, kc = cid & 7;
      bv[j] = *(const uint4*)(bsrc + (size_t)col * NUMELK + kc * 8);
    }

    // ---- consume prefetched A (vmcnt wait lands here, after a full compute phase)
    bf16x8 alo, ahi;
    alo[0] = f2bf(va0[0]); alo[1] = f2bf(va0[1]); alo[2] = f2bf(va0[2]); alo[3] = f2bf(va0[3]);
    alo[4] = f2bf(va1[0]); alo[5] = f2bf(va1[1]); alo[6] = f2bf(va1[2]); alo[7] = f2bf(va1[3]);
    ahi[0] = f2bf(va2[0]); ahi[1] = f2bf(va2[1]); ahi[2] = f2bf(va2[2]); ahi[3] = f2bf(va2[3]);
    ahi[4] = f2bf(va3[0]); ahi[5] = f2bf(va3[1]); ahi[6] = f2bf(va3[2]); ahi[7] = f2bf(va3[3]);

    __syncthreads();   // barrier-1: previous iteration's ds_reads complete

    *(bf16x8*)&Alds[arow * BK + (((2 * aq)     ^ (arow & 7)) << 3)] = alo;
    *(bf16x8*)&Alds[arow * BK + (((2 * aq + 1) ^ (arow & 7)) << 3)] = ahi;
#pragma unroll
    for (int j = 0; j < 4; ++j) {
      int cid = t + j * 512;
      int col = cid >> 3, kc = cid & 7;
      *(uint4*)&Blds[col * BK + ((kc ^ (col & 7)) << 3)] = bv[j];
    }

    __syncthreads();   // barrier-2: LDS visible

    // ---- prefetch A for kt+1 (in flight across the MFMA phase below)
    if (kt + 1 < niter) {
      const int kg2 = kg + BK;
      const float* A; int ka;
      if (kg2 < HALF_K) { A = white; ka = kg2; } else { A = black; ka = kg2 - HALF_K; }
      const float* asrc = A + arow_off + ka;
      va0 = ((const fvec4*)asrc)[0];
      va1 = ((const fvec4*)asrc)[1];
      va2 = ((const fvec4*)asrc)[2];
      va3 = ((const fvec4*)asrc)[3];
    }

    // ---- compute
#pragma unroll
    for (int kstep = 0; kstep < 2; ++kstep) {
      bf16x8 af[4], bfr[4];
      const int kc = kstep * 4 + l4;
#pragma unroll
      for (int mf = 0; mf < 4; ++mf) {
        int row = wm * 64 + mf * 16 + l15;
        af[mf] = *(const bf16x8*)&Alds[row * BK + ((kc ^ (row & 7)) << 3)];
      }
#pragma unroll
      for (int nf = 0; nf < 4; ++nf) {
        int col = wn * 64 + nf * 16 + l15;
        bfr[nf] = *(const bf16x8*)&Blds[col * BK + ((kc ^ (col & 7)) << 3)];
      }
#pragma unroll
      for (int mf = 0; mf < 4; ++mf)
#pragma unroll
        for (int nf = 0; nf < 4; ++nf)
          acc[mf][nf] = __builtin_amdgcn_mfma_f32_16x16x32_bf16(af[mf], bfr[nf], acc[mf][nf], 0, 0, 0);
    }
    // no trailing barrier: next iteration's barrier-1 protects the LDS overwrite
  }

  // ---- epilogue: C/D layout col=lane&15, row=(lane>>4)*4+r   [m89]
  float* P = partial + ((size_t)ks * BATCH + m0) * 256;
#pragma unroll
  for (int mf = 0; mf < 4; ++mf) {
    int row = wm * 64 + mf * 16 + l4 * 4;
#pragma unroll
    for (int nf = 0; nf < 4; ++nf) {
      int col = wn * 64 + nf * 16 + l15;
#pragma unroll
      for (int r = 0; r < 4; ++r)
        P[(size_t)(row + r) * 256 + col] = acc[mf][nf][r];
    }
  }
}

// ---------------- tail: partial-reduce + pov mix + relu + fc0..fc3 ----------------
__global__ __launch_bounds__(256)
void nnue_tail(const float* __restrict__ partial, int S,
               const float* __restrict__ pov,
               const float* __restrict__ waffb, const float* __restrict__ baffb,
               const float* __restrict__ fc0W, const float* __restrict__ fc0b,
               const float* __restrict__ fc1W, const float* __restrict__ fc1b,
               const float* __restrict__ fc2W, const float* __restrict__ fc2b,
               const float* __restrict__ fc3W, const float* __restrict__ fc3b,
               float* __restrict__ out) {
  __shared__ float w0s[32 * 256];   // stored at [(j<<8) | ((k+j)&255)]
  __shared__ float w1s[32 * 32];    // [(j<<5) | ((k+j)&31)]
  __shared__ float w2s[32 * 64];    // [(j<<6) | ((k+j)&63)]
  __shared__ float w3s[96];
  __shared__ float b0s[32], b1s[32], b2s[32];
  __shared__ float base_s[4][256];
  __shared__ float b3s;

  const int t = threadIdx.x;
  for (int i = t; i < 8192; i += 256) { int j = i >> 8, k = i & 255; w0s[(j << 8) | ((k + j) & 255)] = fc0W[i]; }
  for (int i = t; i < 1024; i += 256) { int j = i >> 5, k = i & 31;  w1s[(j << 5) | ((k + j) & 31)]  = fc1W[i]; }
  for (int i = t; i < 2048; i += 256) { int j = i >> 6, k = i & 63;  w2s[(j << 6) | ((k + j) & 63)]  = fc2W[i]; }
  if (t < 96) w3s[t] = fc3W[t];
  if (t < 32) { b0s[t] = fc0b[t]; b1s[t] = fc1b[t]; b2s[t] = fc2b[t]; }
  if (t == 0) b3s = fc3b[0];
  __syncthreads();

  const int wid = t >> 6, lane = t & 63;
  const int m = blockIdx.x * 4 + wid;
  const float pv = pov[m];

  // lane l holds concat[w_,b_] cols 4l..4l+3 (summed over K-splits, +bias)
  float val[4];
  {
    const float* p = partial + (size_t)m * 256 + lane * 4;
    fvec4 a = *(const fvec4*)p;
    for (int s = 1; s < S; ++s) a += *(const fvec4*)(p + (size_t)s * BATCH * 256);
    const int c0 = lane * 4;
#pragma unroll
    for (int j = 0; j < 4; ++j) {
      int c = c0 + j;
      float bias = (c < 128) ? waffb[c] : baffb[c - 128];
      val[j] = a[j] + bias;
    }
  }
#pragma unroll
  for (int j = 0; j < 4; ++j) {
    float other = __shfl(val[j], lane ^ 32, 64);   // partner holds the b_/w_ counterpart
    if (lane < 32) {
      int c = lane * 4 + j;
      float w = val[j], b = other;
      base_s[wid][c]       = fmaxf(pv * w + (1.f - pv) * b, 0.f);
      base_s[wid][c + 128] = fmaxf(pv * b + (1.f - pv) * w, 0.f);
    }
  }
  __syncthreads();

  const int j = lane & 31, half = lane >> 5;
  const float* bs = &base_s[wid][0];

  // fc0: each (j,half) pair sums 128 terms, then combines across halves
  float s0 = 0.f;
  for (int k = 0; k < 128; ++k) {
    int kk = half * 128 + k;
    s0 += bs[kk] * w0s[(j << 8) | ((kk + j) & 255)];
  }
  s0 += __shfl(s0, lane ^ 32, 64);
  float x0 = fmaxf(s0 + b0s[j], 0.f);

  // fc1 (32x32)
  float s1 = 0.f;
  for (int k = 0; k < 32; ++k)
    s1 += __shfl(x0, k, 64) * w1s[(j << 5) | ((k + j) & 31)];
  float x1 = fmaxf(s1 + b1s[j], 0.f);

  // fc2 (32x64), input = [x0, x1]
  float s2 = 0.f;
  for (int k = 0; k < 32; ++k) {
    s2 += __shfl(x0, k, 64) * w2s[(j << 6) | ((k + j) & 63)];
    s2 += __shfl(x1, k, 64) * w2s[(j << 6) | ((k + 32 + j) & 63)];
  }
  float x2 = fmaxf(s2 + b2s[j], 0.f);

  // fc3 (1x96), input = [x0, x1, x2]
  float s3 = 0.f;
  for (int k = 0; k < 32; ++k) {
    s3 += __shfl(x0, k, 64) * w3s[k];
    s3 += __shfl(x1, k, 64) * w3s[32 + k];
    s3 += __shfl(x2, k, 64) * w3s[64 + k];
  }
  if (lane == 0) out[m] = s3 + b3s;
}

extern "C" void kernel_launch(void* const* d_in, const int* in_sizes, int n_in,
                              void* d_out, int out_size, void* d_ws, size_t ws_size,
                              hipStream_t stream) {
  const float* pov   = (const float*)d_in[0];
  const float* white = (const float*)d_in[1];
  const float* black = (const float*)d_in[2];
  const float* wW    = (const float*)d_in[3];
  const float* wb    = (const float*)d_in[4];
  const float* bW    = (const float*)d_in[5];
  const float* bb    = (const float*)d_in[6];
  const float* fc0W  = (const float*)d_in[7];
  const float* fc0b  = (const float*)d_in[8];
  const float* fc1W  = (const float*)d_in[9];
  const float* fc1b  = (const float*)d_in[10];
  const float* fc2W  = (const float*)d_in[11];
  const float* fc2b  = (const float*)d_in[12];
  const float* fc3W  = (const float*)d_in[13];
  const float* fc3b  = (const float*)d_in[14];
  float* out = (float*)d_out;

  short* Bws = (short*)d_ws;
  const size_t BWS_BYTES = (size_t)256 * NUMELK * 2;      // 25,165,824
  float* partial = (float*)((char*)d_ws + BWS_BYTES);
  const size_t PART1 = (size_t)BATCH * 256 * 4;           // 8,388,608

  int S = 8;                                              // K-split factor
  if (ws_size < BWS_BYTES + 8 * PART1) S = 4;
  if (ws_size < BWS_BYTES + 4 * PART1) S = 2;
  if (ws_size < BWS_BYTES + 2 * PART1) S = 1;

  nnue_prep<<<dim3(48, 256), 256, 0, stream>>>(wW, bW, Bws);
  nnue_gemm<<<dim3(BATCH / BM, S), 512, 0, stream>>>(white, black, Bws, partial, NUMELK / S);
  nnue_tail<<<dim3(BATCH / 4), 256, 0, stream>>>(partial, S, pov, wb, bb,
      fc0W, fc0b, fc1W, fc1b, fc2W, fc2b, fc3W, fc3b, out);
}

// Round 3
// 480.118 us; speedup vs baseline: 1.7157x; 1.7157x over previous
//
#include <hip/hip_runtime.h>
#include <hip/hip_bf16.h>
#include <stdint.h>

typedef float f32x4 __attribute__((ext_vector_type(4)));
typedef float fvec4 __attribute__((ext_vector_type(4)));
typedef short bf16x8 __attribute__((ext_vector_type(8)));

#define HALF_K 24576
#define NUMELK 49152
#define BATCH  8192
#define BM 128
#define BK 64

__device__ __forceinline__ short f2bf(float f) {
  __hip_bfloat16 h = __float2bfloat16(f);
  return __builtin_bit_cast(short, h);
}

// ---------------- prep: Bws[256][49152] bf16 ----------------
// n<128 : Bws[n][k] = w_aff_W[n][k]           (combined-K order == w_feat order)
// n>=128: Bws[n][k] = b_aff_W[n-128][k<24576 ? k+24576 : k-24576]  (halves swapped)
__global__ __launch_bounds__(256)
void nnue_prep(const float* __restrict__ wW, const float* __restrict__ bW,
               short* __restrict__ Bws) {
  int k = (blockIdx.x * 256 + threadIdx.x) * 4;   // grid.x = 12288/256 = 48
  int n = blockIdx.y;                              // 0..255
  const float* src;
  if (n < 128) {
    src = wW + (size_t)n * NUMELK + k;
  } else {
    int kk = (k < HALF_K) ? (k + HALF_K) : (k - HALF_K);
    src = bW + (size_t)(n - 128) * NUMELK + kk;
  }
  fvec4 v = *(const fvec4*)src;
  unsigned a0 = (unsigned)(unsigned short)f2bf(v[0]) | ((unsigned)(unsigned short)f2bf(v[1]) << 16);
  unsigned a1 = (unsigned)(unsigned short)f2bf(v[2]) | ((unsigned)(unsigned short)f2bf(v[3]) << 16);
  uint2 o; o.x = a0; o.y = a1;
  *(uint2*)(Bws + (size_t)n * NUMELK + k) = o;
}

// ---------------- main GEMM: [8192 x 49152] x [49152 x 256] ----------------
// 2-phase double-buffered pipeline (T3 minimum recipe):
//   prologue: load tile0 -> regs -> cvt -> ds_write buf0 -> barrier
//   iter t  : issue global loads for t+1 (regs); ds_read+MFMA on buf[t&1];
//             cvt+ds_write into buf[(t+1)&1]; ONE barrier.
// Loads are in flight across the whole compute phase -> latency hidden.
__global__ __launch_bounds__(512, 2)
void nnue_gemm(const float* __restrict__ white, const float* __restrict__ black,
               const short* __restrict__ Bws, float* __restrict__ partial,
               int kchunk, int S) {
  __shared__ short Alds[2 * BM * BK];    // bf16 [buf][row][k], chunk-XOR swizzled
  __shared__ short Blds[2 * 256 * BK];   // bf16 [buf][col][k], chunk-XOR swizzled

  const int t    = threadIdx.x;
  const int lane = t & 63;
  const int wid  = t >> 6;

  // XCD-grouped decode: all blocks on one XCD share the same ks (B chunk)
  int bid = blockIdx.x;
  int mt, ks;
  if (S == 4) {            // 256 blocks: xcd j -> ks=j>>1, 32 consecutive mt
    int xcd = bid & 7, i = bid >> 3;
    ks = xcd >> 1;
    mt = ((xcd & 1) << 5) + i;
  } else if (S == 8) {     // 512 blocks: xcd j -> ks=j
    ks = bid & 7;
    mt = bid >> 3;
  } else {
    mt = bid & 63;
    ks = bid >> 6;
  }
  const int m0 = mt * BM;
  const int k0 = ks * kchunk;

  f32x4 acc[4][4];
  const f32x4 zero = {0.f, 0.f, 0.f, 0.f};
#pragma unroll
  for (int i = 0; i < 4; ++i)
#pragma unroll
    for (int j = 0; j < 4; ++j) acc[i][j] = zero;

  const int arow = t >> 2;   // 0..127
  const int aq   = t & 3;    // 16 floats each
  const int wm = wid >> 2, wn = wid & 3;
  const int l15 = lane & 15, l4 = lane >> 4;

  const size_t arow_off = (size_t)(m0 + arow) * HALF_K + aq * 16;
  const int niter = kchunk / BK;

  // staging registers (1 tile in flight)
  fvec4 va0, va1, va2, va3;
  uint4 bv0, bv1, bv2, bv3;

  const int bcol0 = t >> 3,          bkc0 = t & 7;         // j=0
  const int bcol1 = (t + 512) >> 3,  bkc1 = t & 7;         // j=1  (cid&7 == t&7)
  const int bcol2 = (t + 1024) >> 3, bkc2 = t & 7;
  const int bcol3 = (t + 1536) >> 3, bkc3 = t & 7;

  auto issue_loads = [&](int kg) {
    const float* A; int ka;
    if (kg < HALF_K) { A = white; ka = kg; } else { A = black; ka = kg - HALF_K; }
    const float* asrc = A + arow_off + ka;
    va0 = ((const fvec4*)asrc)[0];
    va1 = ((const fvec4*)asrc)[1];
    va2 = ((const fvec4*)asrc)[2];
    va3 = ((const fvec4*)asrc)[3];
    const short* bsrc = Bws + kg;
    bv0 = *(const uint4*)(bsrc + (size_t)bcol0 * NUMELK + bkc0 * 8);
    bv1 = *(const uint4*)(bsrc + (size_t)bcol1 * NUMELK + bkc1 * 8);
    bv2 = *(const uint4*)(bsrc + (size_t)bcol2 * NUMELK + bkc2 * 8);
    bv3 = *(const uint4*)(bsrc + (size_t)bcol3 * NUMELK + bkc3 * 8);
  };

  auto write_tile = [&](int buf) {
    bf16x8 alo, ahi;
    alo[0] = f2bf(va0[0]); alo[1] = f2bf(va0[1]); alo[2] = f2bf(va0[2]); alo[3] = f2bf(va0[3]);
    alo[4] = f2bf(va1[0]); alo[5] = f2bf(va1[1]); alo[6] = f2bf(va1[2]); alo[7] = f2bf(va1[3]);
    ahi[0] = f2bf(va2[0]); ahi[1] = f2bf(va2[1]); ahi[2] = f2bf(va2[2]); ahi[3] = f2bf(va2[3]);
    ahi[4] = f2bf(va3[0]); ahi[5] = f2bf(va3[1]); ahi[6] = f2bf(va3[2]); ahi[7] = f2bf(va3[3]);
    short* Ab = Alds + buf * (BM * BK);
    short* Bb = Blds + buf * (256 * BK);
    *(bf16x8*)&Ab[arow * BK + (((2 * aq)     ^ (arow & 7)) << 3)] = alo;
    *(bf16x8*)&Ab[arow * BK + (((2 * aq + 1) ^ (arow & 7)) << 3)] = ahi;
    *(uint4*)&Bb[bcol0 * BK + ((bkc0 ^ (bcol0 & 7)) << 3)] = bv0;
    *(uint4*)&Bb[bcol1 * BK + ((bkc1 ^ (bcol1 & 7)) << 3)] = bv1;
    *(uint4*)&Bb[bcol2 * BK + ((bkc2 ^ (bcol2 & 7)) << 3)] = bv2;
    *(uint4*)&Bb[bcol3 * BK + ((bkc3 ^ (bcol3 & 7)) << 3)] = bv3;
  };

  // prologue
  issue_loads(k0);
  write_tile(0);
  __syncthreads();

  for (int kt = 0; kt < niter; ++kt) {
    const int cur = kt & 1;
    const bool hn = (kt + 1 < niter);
    if (hn) issue_loads(k0 + (kt + 1) * BK);   // in flight across compute below

    const short* Ab = Alds + cur * (BM * BK);
    const short* Bb = Blds + cur * (256 * BK);
#pragma unroll
    for (int kstep = 0; kstep < 2; ++kstep) {
      bf16x8 af[4], bfr[4];
      const int kc = kstep * 4 + l4;
#pragma unroll
      for (int mf = 0; mf < 4; ++mf) {
        int row = wm * 64 + mf * 16 + l15;
        af[mf] = *(const bf16x8*)&Ab[row * BK + ((kc ^ (row & 7)) << 3)];
      }
#pragma unroll
      for (int nf = 0; nf < 4; ++nf) {
        int col = wn * 64 + nf * 16 + l15;
        bfr[nf] = *(const bf16x8*)&Bb[col * BK + ((kc ^ (col & 7)) << 3)];
      }
#pragma unroll
      for (int mf = 0; mf < 4; ++mf)
#pragma unroll
        for (int nf = 0; nf < 4; ++nf)
          acc[mf][nf] = __builtin_amdgcn_mfma_f32_16x16x32_bf16(af[mf], bfr[nf], acc[mf][nf], 0, 0, 0);
    }

    if (hn) write_tile(cur ^ 1);   // vmcnt wait lands here, after compute
    __syncthreads();               // single barrier per iteration
  }

  // ---- epilogue: C/D layout col=lane&15, row=(lane>>4)*4+r   [m89]
  float* P = partial + ((size_t)ks * BATCH + m0) * 256;
#pragma unroll
  for (int mf = 0; mf < 4; ++mf) {
    int row = wm * 64 + mf * 16 + l4 * 4;
#pragma unroll
    for (int nf = 0; nf < 4; ++nf) {
      int col = wn * 64 + nf * 16 + l15;
#pragma unroll
      for (int r = 0; r < 4; ++r)
        P[(size_t)(row + r) * 256 + col] = acc[mf][nf][r];
    }
  }
}

// ---------------- tail: partial-reduce + pov mix + relu + fc0..fc3 ----------------
__global__ __launch_bounds__(256)
void nnue_tail(const float* __restrict__ partial, int S,
               const float* __restrict__ pov,
               const float* __restrict__ waffb, const float* __restrict__ baffb,
               const float* __restrict__ fc0W, const float* __restrict__ fc0b,
               const float* __restrict__ fc1W, const float* __restrict__ fc1b,
               const float* __restrict__ fc2W, const float* __restrict__ fc2b,
               const float* __restrict__ fc3W, const float* __restrict__ fc3b,
               float* __restrict__ out) {
  __shared__ float w0s[32 * 256];   // stored at [(j<<8) | ((k+j)&255)]
  __shared__ float w1s[32 * 32];    // [(j<<5) | ((k+j)&31)]
  __shared__ float w2s[32 * 64];    // [(j<<6) | ((k+j)&63)]
  __shared__ float w3s[96];
  __shared__ float b0s[32], b1s[32], b2s[32];
  __shared__ float base_s[4][256];
  __shared__ float b3s;

  const int t = threadIdx.x;
  for (int i = t; i < 8192; i += 256) { int j = i >> 8, k = i & 255; w0s[(j << 8) | ((k + j) & 255)] = fc0W[i]; }
  for (int i = t; i < 1024; i += 256) { int j = i >> 5, k = i & 31;  w1s[(j << 5) | ((k + j) & 31)]  = fc1W[i]; }
  for (int i = t; i < 2048; i += 256) { int j = i >> 6, k = i & 63;  w2s[(j << 6) | ((k + j) & 63)]  = fc2W[i]; }
  if (t < 96) w3s[t] = fc3W[t];
  if (t < 32) { b0s[t] = fc0b[t]; b1s[t] = fc1b[t]; b2s[t] = fc2b[t]; }
  if (t == 0) b3s = fc3b[0];
  __syncthreads();

  const int wid = t >> 6, lane = t & 63;
  const int m = blockIdx.x * 4 + wid;
  const float pv = pov[m];

  // lane l holds concat[w_,b_] cols 4l..4l+3 (summed over K-splits, +bias)
  float val[4];
  {
    const float* p = partial + (size_t)m * 256 + lane * 4;
    fvec4 a = *(const fvec4*)p;
    for (int s = 1; s < S; ++s) a += *(const fvec4*)(p + (size_t)s * BATCH * 256);
    const int c0 = lane * 4;
#pragma unroll
    for (int j = 0; j < 4; ++j) {
      int c = c0 + j;
      float bias = (c < 128) ? waffb[c] : baffb[c - 128];
      val[j] = a[j] + bias;
    }
  }
#pragma unroll
  for (int j = 0; j < 4; ++j) {
    float other = __shfl(val[j], lane ^ 32, 64);   // partner holds the b_/w_ counterpart
    if (lane < 32) {
      int c = lane * 4 + j;
      float w = val[j], b = other;
      base_s[wid][c]       = fmaxf(pv * w + (1.f - pv) * b, 0.f);
      base_s[wid][c + 128] = fmaxf(pv * b + (1.f - pv) * w, 0.f);
    }
  }
  __syncthreads();

  const int j = lane & 31, half = lane >> 5;
  const float* bs = &base_s[wid][0];

  // fc0: each (j,half) pair sums 128 terms, then combines across halves
  float s0 = 0.f;
  for (int k = 0; k < 128; ++k) {
    int kk = half * 128 + k;
    s0 += bs[kk] * w0s[(j << 8) | ((kk + j) & 255)];
  }
  s0 += __shfl(s0, lane ^ 32, 64);
  float x0 = fmaxf(s0 + b0s[j], 0.f);

  // fc1 (32x32)
  float s1 = 0.f;
  for (int k = 0; k < 32; ++k)
    s1 += __shfl(x0, k, 64) * w1s[(j << 5) | ((k + j) & 31)];
  float x1 = fmaxf(s1 + b1s[j], 0.f);

  // fc2 (32x64), input = [x0, x1]
  float s2 = 0.f;
  for (int k = 0; k < 32; ++k) {
    s2 += __shfl(x0, k, 64) * w2s[(j << 6) | ((k + j) & 63)];
    s2 += __shfl(x1, k, 64) * w2s[(j << 6) | ((k + 32 + j) & 63)];
  }
  float x2 = fmaxf(s2 + b2s[j], 0.f);

  // fc3 (1x96), input = [x0, x1, x2]
  float s3 = 0.f;
  for (int k = 0; k < 32; ++k) {
    s3 += __shfl(x0, k, 64) * w3s[k];
    s3 += __shfl(x1, k, 64) * w3s[32 + k];
    s3 += __shfl(x2, k, 64) * w3s[64 + k];
  }
  if (lane == 0) out[m] = s3 + b3s;
}

extern "C" void kernel_launch(void* const* d_in, const int* in_sizes, int n_in,
                              void* d_out, int out_size, void* d_ws, size_t ws_size,
                              hipStream_t stream) {
  const float* pov   = (const float*)d_in[0];
  const float* white = (const float*)d_in[1];
  const float* black = (const float*)d_in[2];
  const float* wW    = (const float*)d_in[3];
  const float* wb    = (const float*)d_in[4];
  const float* bW    = (const float*)d_in[5];
  const float* bb    = (const float*)d_in[6];
  const float* fc0W  = (const float*)d_in[7];
  const float* fc0b  = (const float*)d_in[8];
  const float* fc1W  = (const float*)d_in[9];
  const float* fc1b  = (const float*)d_in[10];
  const float* fc2W  = (const float*)d_in[11];
  const float* fc2b  = (const float*)d_in[12];
  const float* fc3W  = (const float*)d_in[13];
  const float* fc3b  = (const float*)d_in[14];
  float* out = (float*)d_out;

  short* Bws = (short*)d_ws;
  const size_t BWS_BYTES = (size_t)256 * NUMELK * 2;      // 25,165,824
  float* partial = (float*)((char*)d_ws + BWS_BYTES);
  const size_t PART1 = (size_t)BATCH * 256 * 4;           // 8,388,608

  int S = 4;                                              // K-split: 256 blocks = 1/CU
  if (ws_size < BWS_BYTES + 4 * PART1) S = 2;
  if (ws_size < BWS_BYTES + 2 * PART1) S = 1;

  nnue_prep<<<dim3(48, 256), 256, 0, stream>>>(wW, bW, Bws);
  nnue_gemm<<<dim3(64 * S), 512, 0, stream>>>(white, black, Bws, partial, NUMELK / S, S);
  nnue_tail<<<dim3(BATCH / 4), 256, 0, stream>>>(partial, S, pov, wb, bb,
      fc0W, fc0b, fc1W, fc1b, fc2W, fc2b, fc3W, fc3b, out);
}